// Round 1
// baseline (545.900 us; speedup 1.0000x reference)
//
#include <hip/hip_runtime.h>
#include <hip/hip_bf16.h>

typedef __attribute__((ext_vector_type(8))) short short8;
typedef __attribute__((ext_vector_type(4))) float floatx4;

#define GLOBAL_AS __attribute__((address_space(1)))
#define LDS_AS    __attribute__((address_space(3)))

__device__ __forceinline__ unsigned short f2bf_rne(float x) {
  unsigned int u = __float_as_uint(x);
  u += 0x7fffu + ((u >> 16) & 1u);
  return (unsigned short)(u >> 16);
}

// ---------------- cast fp32 -> bf16 (8 elems/thread) ----------------
__global__ void cast_f32_bf16_kernel(const float* __restrict__ in,
                                     unsigned short* __restrict__ out, int n8) {
  int i = blockIdx.x * 256 + threadIdx.x;
  if (i >= n8) return;
  const float4* p = (const float4*)in;
  float4 v0 = p[2 * i], v1 = p[2 * i + 1];
  short8 o;
  o[0] = (short)f2bf_rne(v0.x); o[1] = (short)f2bf_rne(v0.y);
  o[2] = (short)f2bf_rne(v0.z); o[3] = (short)f2bf_rne(v0.w);
  o[4] = (short)f2bf_rne(v1.x); o[5] = (short)f2bf_rne(v1.y);
  o[6] = (short)f2bf_rne(v1.z); o[7] = (short)f2bf_rne(v1.w);
  *(short8*)(out + 8 * (size_t)i) = o;
}

// ---------------- transpose + cast: in[R][C] fp32 -> out[C][R] bf16 ----------------
__global__ void transpose_cast_kernel(const float* __restrict__ in,
                                      unsigned short* __restrict__ out, int R, int C) {
  __shared__ unsigned short tile[32][33];
  int tx = threadIdx.x & 31, ty = threadIdx.x >> 5;
  int r0 = blockIdx.y * 32, c0 = blockIdx.x * 32;
#pragma unroll
  for (int j = 0; j < 32; j += 8)
    tile[ty + j][tx] = f2bf_rne(in[(size_t)(r0 + ty + j) * C + c0 + tx]);
  __syncthreads();
#pragma unroll
  for (int j = 0; j < 32; j += 8)
    out[(size_t)(c0 + ty + j) * R + r0 + tx] = tile[tx][ty + j];
}

// ---------------- bias1 = bg @ Gs + bgs ----------------
__global__ void init_vec_kernel(const float* __restrict__ src, float* __restrict__ dst) {
  int i = blockIdx.x * 256 + threadIdx.x;
  dst[i] = src[i];
}
__global__ void bias1_accum_kernel(const float* __restrict__ bg, const float* __restrict__ Gs,
                                   float* __restrict__ bias1) {
  int j = blockIdx.x * 256 + threadIdx.x;   // 0..1023
  int k0 = blockIdx.y * 256;
  float acc = 0.f;
  for (int k = 0; k < 256; ++k) acc += bg[k0 + k] * Gs[(size_t)(k0 + k) * 1024 + j];
  atomicAdd(&bias1[j], acc);
}

// ---------------- dec_fea = s_t_hat @ Wdec + bdec (fp32) ----------------
__global__ void init_dec_kernel(const float* __restrict__ bdec, float* __restrict__ dec) {
  int i = blockIdx.x * 256 + threadIdx.x;   // 32768
  dec[i] = bdec[i & 1023];
}
__global__ void dec_accum_kernel(const float* __restrict__ sth, const float* __restrict__ Wdec,
                                 float* __restrict__ dec) {
  __shared__ float ss[32][128];
  const int tid = threadIdx.x;
  const int k0 = blockIdx.y * 128;
  for (int i = tid; i < 32 * 128; i += 256) {
    int bb = i >> 7, kk = i & 127;
    ss[bb][kk] = sth[bb * 1024 + k0 + kk];
  }
  __syncthreads();
  const int j = blockIdx.x * 256 + tid;
  float acc[32];
#pragma unroll
  for (int b = 0; b < 32; ++b) acc[b] = 0.f;
  for (int kk = 0; kk < 128; ++kk) {
    float w = Wdec[(size_t)(k0 + kk) * 1024 + j];
#pragma unroll
    for (int b = 0; b < 32; ++b) acc[b] += ss[b][kk] * w;
  }
  for (int b = 0; b < 32; ++b) atomicAdd(&dec[b * 1024 + j], acc[b]);
}

// ---------------- m97-style GEMM: C[M,N] = A[M,K] @ BT[N,K]^T (+bias[N]) ----------------
template <bool HAS_BIAS>
__global__ __launch_bounds__(256, 2) void gemm_bt_kernel(
    const unsigned short* __restrict__ A, const unsigned short* __restrict__ BT,
    const float* __restrict__ bias, float* __restrict__ C, int M, int N, int K) {
  __shared__ unsigned short lds_a[128 * 32];
  __shared__ unsigned short lds_b[128 * 32];
  const int tid = threadIdx.x;
  const int lane = tid & 63;
  const int wave = tid >> 6;
  const int wm = wave >> 1, wn = wave & 1;
  const int quad = lane >> 4, col = lane & 15;
  const int m0 = blockIdx.y * 128, n0 = blockIdx.x * 128;

  floatx4 acc[4][4] = {};

  const int srow = tid >> 2;           // 0..63
  const int skoff = (tid & 3) * 8;     // 0,8,16,24
  const unsigned short* a_ptr = A + (size_t)(m0 + srow) * K + skoff;
  const unsigned short* b_ptr = BT + (size_t)(n0 + srow) * K + skoff;
  const size_t rowskip = (size_t)64 * K;
  char* la_dst = (char*)lds_a + tid * 16;
  char* lb_dst = (char*)lds_b + tid * 16;

  for (int kt = 0; kt < K; kt += 32) {
    __syncthreads();
    __builtin_amdgcn_global_load_lds((const GLOBAL_AS void*)(a_ptr), (LDS_AS void*)(la_dst), 16, 0, 0);
    __builtin_amdgcn_global_load_lds((const GLOBAL_AS void*)(a_ptr + rowskip), (LDS_AS void*)(la_dst + 4096), 16, 0, 0);
    __builtin_amdgcn_global_load_lds((const GLOBAL_AS void*)(b_ptr), (LDS_AS void*)(lb_dst), 16, 0, 0);
    __builtin_amdgcn_global_load_lds((const GLOBAL_AS void*)(b_ptr + rowskip), (LDS_AS void*)(lb_dst + 4096), 16, 0, 0);
    a_ptr += 32; b_ptr += 32;
    __syncthreads();
    short8 af[4], bf[4];
#pragma unroll
    for (int t = 0; t < 4; ++t) {
      af[t] = *(const short8*)((const char*)lds_a + (wm * 64 + t * 16 + col) * 64 + quad * 16);
      bf[t] = *(const short8*)((const char*)lds_b + (wn * 64 + t * 16 + col) * 64 + quad * 16);
    }
#pragma unroll
    for (int tm = 0; tm < 4; ++tm)
#pragma unroll
      for (int tn = 0; tn < 4; ++tn)
        acc[tm][tn] = __builtin_amdgcn_mfma_f32_16x16x32_bf16(af[tm], bf[tn], acc[tm][tn], 0, 0, 0);
  }

#pragma unroll
  for (int tm = 0; tm < 4; ++tm) {
    const int mg = m0 + wm * 64 + tm * 16 + quad * 4;
#pragma unroll
    for (int tn = 0; tn < 4; ++tn) {
      const int ng = n0 + wn * 64 + tn * 16 + col;
      const float bv = HAS_BIAS ? bias[ng] : 0.0f;
#pragma unroll
      for (int r = 0; r < 4; ++r)
        C[(size_t)(mg + r) * N + ng] = acc[tm][tn][r] + bv;
    }
  }
}

// ---------------- scores[r] = sum_d tanh(w[r,d] + dec[b,d] + cov[r]) * v[d] ----------------
__global__ void scores_kernel(const float* __restrict__ w, const float* __restrict__ dec,
                              const float* __restrict__ cov, const float* __restrict__ v,
                              float* __restrict__ scores) {
  const int row = blockIdx.x * 4 + (threadIdx.x >> 6);
  const int lane = threadIdx.x & 63;
  const int b = row / 196;
  const float cv = cov[row];
  const float* wr = w + (size_t)row * 1024;
  const float* dr = dec + b * 1024;
  float acc = 0.f;
#pragma unroll
  for (int i = 0; i < 4; ++i) {
    int d = i * 256 + lane * 4;
    float4 wv = *(const float4*)(wr + d);
    float4 dv = *(const float4*)(dr + d);
    float4 vv = *(const float4*)(v + d);
    acc += tanhf(wv.x + dv.x + cv) * vv.x;
    acc += tanhf(wv.y + dv.y + cv) * vv.y;
    acc += tanhf(wv.z + dv.z + cv) * vv.z;
    acc += tanhf(wv.w + dv.w + cv) * vv.w;
  }
  for (int off = 32; off > 0; off >>= 1) acc += __shfl_down(acc, off, 64);
  if (lane == 0) scores[row] = acc;
}

// ---------------- softmax over 196 + context + coverage ----------------
__global__ void softmax_ctx_kernel(const float* __restrict__ scores,
                                   const float* __restrict__ gstar,
                                   const float* __restrict__ cov, float* __restrict__ out) {
  const int b = blockIdx.x, tid = threadIdx.x;
  const int lane = tid & 63, wid = tid >> 6;
  __shared__ float sal[256];
  __shared__ float red[8];
  float s = (tid < 196) ? scores[b * 196 + tid] : -1e30f;
  float m = s;
  for (int off = 32; off > 0; off >>= 1) m = fmaxf(m, __shfl_xor(m, off, 64));
  if (lane == 0) red[wid] = m;
  __syncthreads();
  m = fmaxf(fmaxf(red[0], red[1]), fmaxf(red[2], red[3]));
  float e = (tid < 196) ? __expf(s - m) : 0.f;
  float t = e;
  for (int off = 32; off > 0; off >>= 1) t += __shfl_xor(t, off, 64);
  if (lane == 0) red[4 + wid] = t;
  __syncthreads();
  const float tot = red[4] + red[5] + red[6] + red[7];
  const float a = e / tot;
  sal[tid] = a;
  if (tid < 196) {
    out[32768 + b * 196 + tid] = cov[b * 196 + tid] + a;          // coverage_new
    out[32768 + 6272 + b * 196 + tid] = a;                        // alpha_a
  }
  __syncthreads();
  const float* gs = gstar + (size_t)b * 196 * 1024 + tid * 4;
  float4 acc = make_float4(0.f, 0.f, 0.f, 0.f);
  for (int t2 = 0; t2 < 196; ++t2) {
    float a2 = sal[t2];
    float4 g = *(const float4*)(gs + (size_t)t2 * 1024);
    acc.x += a2 * g.x; acc.y += a2 * g.y; acc.z += a2 * g.z; acc.w += a2 * g.w;
  }
  *(float4*)(out + b * 1024 + tid * 4) = acc;                     // c_img
}

// ---------------- launch ----------------
extern "C" void kernel_launch(void* const* d_in, const int* in_sizes, int n_in,
                              void* d_out, int out_size, void* d_ws, size_t ws_size,
                              hipStream_t stream) {
  (void)in_sizes; (void)n_in; (void)out_size; (void)ws_size;
  const float* gf   = (const float*)d_in[0];   // [6272, 4096]
  const float* sth  = (const float*)d_in[1];   // [32, 1024]
  const float* cov  = (const float*)d_in[2];   // [6272]
  const float* Wg   = (const float*)d_in[3];   // [4096, 4096]
  const float* bg   = (const float*)d_in[4];   // [4096]
  const float* Gs   = (const float*)d_in[5];   // [4096, 1024]
  const float* bgs  = (const float*)d_in[6];   // [1024]
  const float* Wgs  = (const float*)d_in[7];   // [1024, 1024]
  const float* Wdec = (const float*)d_in[8];   // [1024, 1024]
  const float* bdec = (const float*)d_in[9];   // [1024]
  const float* v    = (const float*)d_in[10];  // [1024]
  float* out = (float*)d_out;

  char* ws = (char*)d_ws;
  // region A: gf_bf16 (51,380,224 B) ; later w_f32 (25,690,112 B)
  // region B: Wg_bf16 (33,554,432 B) ; later g_star_f32 (25,690,112 B)
  // region C: GsT_bf16 (8,388,608 B) ; later WgsT_bf16 (2,097,152 B)
  // region D: C1T_f32 (16,777,216 B) ; later g_star_bf16 (12,845,056 B)
  // region E: C1T_bf16 (8,388,608 B)
  unsigned short* gf_bf  = (unsigned short*)(ws + 0);
  float*          w_f    = (float*)(ws + 0);
  unsigned short* Wg_bf  = (unsigned short*)(ws + 51380224);
  float*          gstar_f = (float*)(ws + 51380224);
  unsigned short* GsT    = (unsigned short*)(ws + 84934656);
  unsigned short* WgsT   = (unsigned short*)(ws + 84934656);
  float*          C1T_f  = (float*)(ws + 93323264);
  unsigned short* gstar_b = (unsigned short*)(ws + 93323264);
  unsigned short* C1T_b  = (unsigned short*)(ws + 110100480);
  float*          bias1  = (float*)(ws + 118489088);
  float*          dec    = (float*)(ws + 118493184);
  float*          scores = (float*)(ws + 118624256);

  // 1. casts / transposes
  cast_f32_bf16_kernel<<<12544, 256, 0, stream>>>(gf, gf_bf, 3211264);       // 25,690,112/8
  cast_f32_bf16_kernel<<<8192, 256, 0, stream>>>(Wg, Wg_bf, 2097152);        // 16,777,216/8
  transpose_cast_kernel<<<dim3(32, 128), 256, 0, stream>>>(Gs, GsT, 4096, 1024);
  // 2. bias1 = bg @ Gs + bgs
  init_vec_kernel<<<4, 256, 0, stream>>>(bgs, bias1);
  bias1_accum_kernel<<<dim3(4, 16), 256, 0, stream>>>(bg, Gs, bias1);
  // 3. GEMM1: C1T[1024,4096] = GsT @ Wg^T
  gemm_bt_kernel<false><<<dim3(32, 8), 256, 0, stream>>>(GsT, Wg_bf, nullptr, C1T_f, 1024, 4096, 4096);
  cast_f32_bf16_kernel<<<2048, 256, 0, stream>>>(C1T_f, C1T_b, 524288);
  // 4. WgsT (region C free after GEMM1)
  transpose_cast_kernel<<<dim3(32, 32), 256, 0, stream>>>(Wgs, WgsT, 1024, 1024);
  // 5. dec_fea = s_t_hat @ Wdec + bdec
  init_dec_kernel<<<128, 256, 0, stream>>>(bdec, dec);
  dec_accum_kernel<<<dim3(4, 8), 256, 0, stream>>>(sth, Wdec, dec);
  // 6. GEMM2: g_star[6272,1024] = gf @ C1 + bias1
  gemm_bt_kernel<true><<<dim3(8, 49), 256, 0, stream>>>(gf_bf, C1T_b, bias1, gstar_f, 6272, 1024, 4096);
  cast_f32_bf16_kernel<<<3136, 256, 0, stream>>>(gstar_f, gstar_b, 802816);
  // 7. GEMM3: w_g_star[6272,1024] = g_star @ Wgs
  gemm_bt_kernel<false><<<dim3(8, 49), 256, 0, stream>>>(gstar_b, WgsT, nullptr, w_f, 6272, 1024, 1024);
  // 8. scores
  scores_kernel<<<1568, 256, 0, stream>>>(w_f, dec, cov, v, scores);
  // 9. softmax + context + coverage
  softmax_ctx_kernel<<<32, 256, 0, stream>>>(scores, gstar_f, cov, out);
}